// Round 2
// baseline (769.310 us; speedup 1.0000x reference)
//
#include <hip/hip_runtime.h>
#include <cstdint>

#define B_ 4
#define N_ 512
#define HID_ 256
#define H_ 8
#define E_ 32
#define SCALE_ 0.17677669529663687f
#define NEG_ (-9.0e15f)

__device__ __forceinline__ void fma4(float4& a, const float4 q, const float4 k) {
  a.x += q.x*k.x; a.y += q.y*k.y; a.z += q.z*k.z; a.w += q.w*k.w;
}
__device__ __forceinline__ float dot4(const float4 a, const float4 b) {
  return a.x*b.x + a.y*b.y + a.z*b.z + a.w*b.w;
}

// ---------------- K/V projection ----------------
// grid (B_*N_/4, 2); block 256. y==0 -> K, y==1 -> V.
// kh[b,j,c] = sum_k in[b,j,k]*W[c,k] + bias[c]
__global__ __launch_bounds__(256) void kv_proj(
    const float* __restrict__ kin, const float* __restrict__ vin,
    const float* __restrict__ Wk, const float* __restrict__ bk,
    const float* __restrict__ Wv, const float* __restrict__ bv,
    float* __restrict__ kh, float* __restrict__ vh)
{
  __shared__ float a_s[4][HID_];
  const int tid = threadIdx.x;
  const int b  = blockIdx.x >> 7;
  const int j0 = (blockIdx.x & 127) * 4;
  const float *src, *W, *bias; float* dst;
  if (blockIdx.y == 0) { src = kin; W = Wk; bias = bk; dst = kh; }
  else                 { src = vin; W = Wv; bias = bv; dst = vh; }
  {
    int r = tid >> 6, c = (tid & 63) * 4;
    *(float4*)&a_s[r][c] = *(const float4*)&src[(size_t)(b*N_ + j0 + r)*HID_ + c];
  }
  __syncthreads();
  const int c = tid;
  float bb = bias[c];
  float acc[4] = {bb, bb, bb, bb};
  for (int k = 0; k < HID_; k += 4) {
    float4 w4 = *(const float4*)&W[(size_t)c*HID_ + k];
    #pragma unroll
    for (int r = 0; r < 4; ++r) {
      float4 a4 = *(const float4*)&a_s[r][k];
      acc[r] += dot4(a4, w4);
    }
  }
  #pragma unroll
  for (int r = 0; r < 4; ++r)
    dst[(size_t)(b*N_ + j0 + r)*HID_ + c] = acc[r];
}

// ---------------- fused attention + edge pipeline ----------------
// grid B_*N_/2 = 1024 blocks, 256 threads. Each block: 2 i-rows.
__global__ __launch_bounds__(256, 4) void fused_graph_attn(
    const float* __restrict__ qin,
    const float* __restrict__ khp, const float* __restrict__ vhp,
    const float* __restrict__ adj, const float* __restrict__ adj1,
    const float* __restrict__ ef, const float* __restrict__ ab,
    const float* __restrict__ Wq, const float* __restrict__ bq,
    const float* __restrict__ Wap, const float* __restrict__ bap,
    const float* __restrict__ Wep, const float* __restrict__ bep,
    const float* __restrict__ Wo, const float* __restrict__ bo,
    const float* __restrict__ Woe,
    const int* __restrict__ use_adj_p,
    float* __restrict__ out, float* __restrict__ eo)
{
  __shared__ float qh_s[2][HID_+4];
  __shared__ float ef_s[2][16][2][E_];   // lane-contiguous: addr = tid*4 floats
  __shared__ float x_s[2][H_][17];
  __shared__ float pj_s[16][2][H_+1];
  __shared__ float wg_s[2][H_][20];
  __shared__ float wl_s[2][H_][20];
  __shared__ float sg_s[2][H_];
  __shared__ float sl_s[2][H_];
  __shared__ float Wap_s[E_][H_];
  __shared__ float Wep_s[H_][E_];
  __shared__ float Woe_s[E_][E_+1];
  __shared__ float bep_s[H_];
  __shared__ float bap_s[E_];
  __shared__ float y_s[2][HID_+4];       // also q staging in prologue

  const int tid = threadIdx.x;
  const int b  = blockIdx.x >> 8;
  const int i0 = (blockIdx.x & 255) * 2;
  const int ua = use_adj_p[0];

  // ---- prologue: small weights + q staging ----
  for (int u = tid; u < E_*H_; u += 256) Wap_s[u>>3][u&7]  = Wap[u];
  for (int u = tid; u < H_*E_; u += 256) Wep_s[u>>5][u&31] = Wep[u];
  for (int u = tid; u < E_*E_; u += 256) Woe_s[u>>5][u&31] = Woe[u];
  if (tid < H_) bep_s[tid] = bep[tid];
  if (tid < E_) bap_s[tid] = bap[tid];
  if (tid < 2*H_) { sg_s[tid>>3][tid&7] = 0.f; sl_s[tid>>3][tid&7] = 0.f; }
  if (tid < 128) {
    int r = tid >> 6, c0 = (tid & 63) * 4;
    *(float4*)&y_s[r][c0] = *(const float4*)&qin[(size_t)(b*N_ + i0 + r)*HID_ + c0];
  }
  __syncthreads();

  // ---- q projection: thread per output column, both rows ----
  {
    const int cc = tid;
    float bqv = bq[cc];
    float a0c = bqv, a1c = bqv;
    for (int k = 0; k < HID_; k += 4) {
      float4 w4 = *(const float4*)&Wq[(size_t)cc*HID_ + k];
      float4 y0 = *(const float4*)&y_s[0][k];
      float4 y1 = *(const float4*)&y_s[1][k];
      a0c += dot4(y0, w4);
      a1c += dot4(y1, w4);
    }
    qh_s[0][cc] = a0c * SCALE_;
    qh_s[1][cc] = a1c * SCALE_;
  }
  __syncthreads();

  // mappings
  const int hA = tid >> 5, iiA = (tid >> 4) & 1, jcA = tid & 15;   // QK
  const int jcE = tid >> 4, ilE = (tid >> 3) & 1, ehE = tid & 7;   // edge
  const int iS = tid >> 7, hS = (tid >> 4) & 7, jcS = tid & 15;    // softmax
  const int hP = tid >> 5, dP = tid & 31;                          // PV / y

  float4 qh_r[8];
  #pragma unroll
  for (int d4 = 0; d4 < 8; ++d4)
    qh_r[d4] = *(const float4*)&qh_s[iiA][hA*32 + d4*4];

  float accg[2] = {0.f, 0.f}, accl[2] = {0.f, 0.f};
  float efr[4];

  for (int ch = 0; ch < 32; ++ch) {
    const int j0 = ch * 16;
    const int buf = ch & 1;
    // ======== phase A: ef load + Wep proj + QK ========
    {
      float4 e4 = *(const float4*)&ef[(((size_t)(b*N_ + j0 + jcE))*N_ + i0 + ilE)*E_ + ehE*4];
      *(float4*)&ef_s[buf][jcE][ilE][ehE*4] = e4;
      efr[0]=e4.x; efr[1]=e4.y; efr[2]=e4.z; efr[3]=e4.w;
      float pp[8];
      #pragma unroll
      for (int h = 0; h < 8; ++h) {
        float4 w4 = *(const float4*)&Wep_s[h][ehE*4];
        pp[h] = dot4(e4, w4);
      }
      #pragma unroll
      for (int m = 1; m <= 4; m <<= 1)
        #pragma unroll
        for (int h = 0; h < 8; ++h)
          pp[h] += __shfl_xor(pp[h], m, 64);
      pj_s[jcE][ilE][ehE] = pp[ehE] + bep_s[ehE];
    }
    {
      const float* kr = &khp[(size_t)(b*N_ + j0 + jcA)*HID_ + hA*32];
      float4 s4 = make_float4(0.f,0.f,0.f,0.f);
      #pragma unroll
      for (int d4 = 0; d4 < 8; ++d4)
        fma4(s4, qh_r[d4], *(const float4*)&kr[d4*4]);
      float xv = s4.x + s4.y + s4.z + s4.w;
      if (ua) {
        float a = adj[(size_t)(b*N_ + i0 + iiA)*N_ + j0 + jcA];
        xv = (a > 0.f ? xv : NEG_) * a;
      }
      x_s[iiA][hA][jcA] = xv;
    }
    __syncthreads();
    // ======== phase B: softmax weights + edge update (Wap) ========
    {
      float xq  = x_s[iS][hS][jcS];
      float pj  = pj_s[jcS][iS][hS];
      float abv = ab[(((size_t)(b*H_ + hS))*N_ + i0 + iS)*N_ + j0 + jcS];
      float a1  = adj1[(size_t)(b*N_ + i0 + iS)*N_ + j0 + jcS];
      float eg = __expf(xq * abv);
      float el = __expf(xq * pj * a1);
      wg_s[iS][hS][jcS] = eg;
      wl_s[iS][hS][jcS] = el;
      float sgp = eg, slp = el;
      #pragma unroll
      for (int m = 1; m <= 8; m <<= 1) {
        sgp += __shfl_xor(sgp, m, 64);
        slp += __shfl_xor(slp, m, 64);
      }
      if (jcS == 0) { sg_s[iS][hS] += sgp; sl_s[iS][hS] += slp; }
    }
    {
      float xr[8];
      #pragma unroll
      for (int h = 0; h < 8; ++h) xr[h] = x_s[ilE][h][jcE];
      float a1 = adj1[(size_t)(b*N_ + i0 + ilE)*N_ + j0 + jcE];
      #pragma unroll
      for (int xk = 0; xk < 4; ++xk) {
        int e = ehE*4 + xk;
        float4 wa0 = *(const float4*)&Wap_s[e][0];
        float4 wa4 = *(const float4*)&Wap_s[e][4];
        float xp = bap_s[e]
          + xr[0]*wa0.x + xr[1]*wa0.y + xr[2]*wa0.z + xr[3]*wa0.w
          + xr[4]*wa4.x + xr[5]*wa4.y + xr[6]*wa4.z + xr[7]*wa4.w;
        efr[xk] += xp * a1;
      }
      *(float4*)&ef_s[buf][jcE][ilE][ehE*4] = *(float4*)efr;
    }
    __syncthreads();
    // ======== phase C: Woe GEMM -> eo, PV accumulate ========
    {
      float tv[32];
      #pragma unroll
      for (int g = 0; g < 8; ++g)
        *(float4*)&tv[g*4] = *(const float4*)&ef_s[buf][jcE][ilE][g*4];
      float o4[4];
      #pragma unroll
      for (int cx = 0; cx < 4; ++cx) {
        int ep = ehE*4 + cx;
        float s = 0.f;
        #pragma unroll
        for (int g = 0; g < 8; ++g) {
          float4 w4 = *(const float4*)&Woe_s[ep][g*4];
          s += tv[g*4+0]*w4.x + tv[g*4+1]*w4.y + tv[g*4+2]*w4.z + tv[g*4+3]*w4.w;
        }
        o4[cx] = s;
      }
      size_t base = (((size_t)(b*N_ + j0 + jcE))*N_ + i0 + ilE)*E_ + ehE*4;
      *(float4*)&eo[base] = *(float4*)o4;
    }
    {
      float ag0 = accg[0], al0 = accl[0], ag1 = accg[1], al1 = accl[1];
      #pragma unroll
      for (int g = 0; g < 4; ++g) {
        float4 vv4;
        vv4.x = vhp[(size_t)(b*N_ + j0 + g*4 + 0)*HID_ + hP*32 + dP];
        vv4.y = vhp[(size_t)(b*N_ + j0 + g*4 + 1)*HID_ + hP*32 + dP];
        vv4.z = vhp[(size_t)(b*N_ + j0 + g*4 + 2)*HID_ + hP*32 + dP];
        vv4.w = vhp[(size_t)(b*N_ + j0 + g*4 + 3)*HID_ + hP*32 + dP];
        float4 wg0 = *(const float4*)&wg_s[0][hP][g*4];
        float4 wl0 = *(const float4*)&wl_s[0][hP][g*4];
        float4 wg1 = *(const float4*)&wg_s[1][hP][g*4];
        float4 wl1 = *(const float4*)&wl_s[1][hP][g*4];
        ag0 += dot4(wg0, vv4); al0 += dot4(wl0, vv4);
        ag1 += dot4(wg1, vv4); al1 += dot4(wl1, vv4);
      }
      accg[0] = ag0; accl[0] = al0; accg[1] = ag1; accl[1] = al1;
    }
  }

  // ---- finalize y rows into LDS ----
  #pragma unroll
  for (int i = 0; i < 2; ++i)
    y_s[i][hP*32 + dP] = accg[i]/sg_s[i][hP] + accl[i]/sl_s[i][hP];
  __syncthreads();

  // ---- output projection (Wo) ----
  {
    const int n = tid;
    float bov = bo[n];
    float a0c = bov, a1c = bov;
    for (int k = 0; k < HID_; k += 4) {
      float4 w4 = *(const float4*)&Wo[(size_t)n*HID_ + k];
      float4 y0 = *(const float4*)&y_s[0][k];
      float4 y1 = *(const float4*)&y_s[1][k];
      a0c += dot4(y0, w4);
      a1c += dot4(y1, w4);
    }
    out[(size_t)(b*N_ + i0 + 0)*HID_ + n] = a0c;
    out[(size_t)(b*N_ + i0 + 1)*HID_ + n] = a1c;
  }
}

extern "C" void kernel_launch(void* const* d_in, const int* in_sizes, int n_in,
                              void* d_out, int out_size, void* d_ws, size_t ws_size,
                              hipStream_t stream) {
  const float* q    = (const float*)d_in[0];
  const float* k    = (const float*)d_in[1];
  const float* v    = (const float*)d_in[2];
  const float* adj  = (const float*)d_in[3];
  const float* adj1 = (const float*)d_in[4];
  const float* ef   = (const float*)d_in[5];
  const float* ab   = (const float*)d_in[6];
  const float* Wq   = (const float*)d_in[7];
  const float* bq   = (const float*)d_in[8];
  const float* Wk   = (const float*)d_in[9];
  const float* bk   = (const float*)d_in[10];
  const float* Wv   = (const float*)d_in[11];
  const float* bv   = (const float*)d_in[12];
  const float* Wap  = (const float*)d_in[13];
  const float* bap  = (const float*)d_in[14];
  const float* Wep  = (const float*)d_in[15];
  const float* bep  = (const float*)d_in[16];
  const float* Wo   = (const float*)d_in[17];
  const float* bo   = (const float*)d_in[18];
  const float* Woe  = (const float*)d_in[19];
  const int* use_adj = (const int*)d_in[20];

  float* out = (float*)d_out;
  float* eo  = out + (size_t)B_*N_*HID_;
  float* kh  = (float*)d_ws;
  float* vh  = kh + (size_t)B_*N_*HID_;

  kv_proj<<<dim3(B_*N_/4, 2), 256, 0, stream>>>(k, v, Wk, bk, Wv, bv, kh, vh);
  fused_graph_attn<<<dim3(B_*N_/2), 256, 0, stream>>>(
      q, kh, vh, adj, adj1, ef, ab, Wq, bq, Wap, bap, Wep, bep, Wo, bo, Woe,
      use_adj, out, eo);
}

// Round 3
// 502.250 us; speedup vs baseline: 1.5317x; 1.5317x over previous
//
#include <hip/hip_runtime.h>
#include <cstdint>

#define B_ 4
#define N_ 512
#define HID_ 256
#define H_ 8
#define E_ 32
#define T_ 4
#define JC_ 16
#define NCH_ 32
#define SCALE_ 0.17677669529663687f
#define NEG_ (-9.0e15f)

__device__ __forceinline__ float dot4(const float4 a, const float4 b) {
  return a.x*b.x + a.y*b.y + a.z*b.z + a.w*b.w;
}
__device__ __forceinline__ void fma4(float4& a, const float4 q, const float4 k) {
  a.x += q.x*k.x; a.y += q.y*k.y; a.z += q.z*k.z; a.w += q.w*k.w;
}
__device__ __forceinline__ void gload_lds16(const void* g, void* l) {
  __builtin_amdgcn_global_load_lds(
      (__attribute__((address_space(1))) void*)(g),
      (__attribute__((address_space(3))) void*)(l), 16, 0, 0);
}

// ---------------- K/V projection: 32x32 register-blocked tiles ----------------
// grid (64, 8, 2), block 256.  dst[m][c] = sum_k A[m][k]*W[c][k] + bias[c]
__global__ __launch_bounds__(256) void kv_proj(
    const float* __restrict__ kin, const float* __restrict__ vin,
    const float* __restrict__ Wk, const float* __restrict__ bk,
    const float* __restrict__ Wv, const float* __restrict__ bv,
    float* __restrict__ kh, float* __restrict__ vh)
{
  __shared__ float At[32][34];
  __shared__ float Wt[32][34];
  const int tid = threadIdx.x;
  const int m0 = blockIdx.x * 32;
  const int c0 = blockIdx.y * 32;
  const float* A    = blockIdx.z ? vin : kin;
  const float* W    = blockIdx.z ? Wv  : Wk;
  const float* bias = blockIdx.z ? bv  : bk;
  float* dst        = blockIdx.z ? vh  : kh;
  const int tx = tid & 15, ty = tid >> 4;
  const int lr = tid >> 3, lc = (tid & 7) * 4;
  float acc[2][2] = {};
  for (int k0 = 0; k0 < HID_; k0 += 32) {
    float4 a4 = *(const float4*)&A[(size_t)(m0+lr)*HID_ + k0 + lc];
    float4 w4 = *(const float4*)&W[(size_t)(c0+lr)*HID_ + k0 + lc];
    __syncthreads();
    At[lc+0][lr]=a4.x; At[lc+1][lr]=a4.y; At[lc+2][lr]=a4.z; At[lc+3][lr]=a4.w;
    Wt[lc+0][lr]=w4.x; Wt[lc+1][lr]=w4.y; Wt[lc+2][lr]=w4.z; Wt[lc+3][lr]=w4.w;
    __syncthreads();
    #pragma unroll
    for (int kk = 0; kk < 32; ++kk) {
      float2 av = *(const float2*)&At[kk][ty*2];
      float2 wv = *(const float2*)&Wt[kk][tx*2];
      acc[0][0] += av.x*wv.x; acc[0][1] += av.x*wv.y;
      acc[1][0] += av.y*wv.x; acc[1][1] += av.y*wv.y;
    }
  }
  float b0 = bias[c0+tx*2], b1 = bias[c0+tx*2+1];
  dst[(size_t)(m0+ty*2+0)*HID_ + c0+tx*2+0] = acc[0][0]+b0;
  dst[(size_t)(m0+ty*2+0)*HID_ + c0+tx*2+1] = acc[0][1]+b1;
  dst[(size_t)(m0+ty*2+1)*HID_ + c0+tx*2+0] = acc[1][0]+b0;
  dst[(size_t)(m0+ty*2+1)*HID_ + c0+tx*2+1] = acc[1][1]+b1;
}

// ---------------- fused attention + edge pipeline ----------------
// grid 512 blocks (XCD-swizzled), 256 threads, T=4 i-rows per block.
__global__ __launch_bounds__(256, 2) void fused_graph_attn(
    const float* __restrict__ qin,
    const float* __restrict__ khp, const float* __restrict__ vhp,
    const float* __restrict__ adj, const float* __restrict__ adj1,
    const float* __restrict__ ef, const float* __restrict__ ab,
    const float* __restrict__ Wq, const float* __restrict__ bq,
    const float* __restrict__ Wap, const float* __restrict__ bap,
    const float* __restrict__ Wep, const float* __restrict__ bep,
    const float* __restrict__ Wo, const float* __restrict__ bo,
    const float* __restrict__ Woe,
    const int* __restrict__ use_adj_p,
    float* __restrict__ out, float* __restrict__ eo)
{
  __shared__ float vh_s[2][JC_][HID_];     // 32 KB, global_load_lds dbuf
  __shared__ float ef_s[2][JC_][T_][16];   // 8 KB, two lane-linear planes
  __shared__ float qh_s[T_][260];
  __shared__ float y_s[T_][260];           // raw q in prologue, y at end
  __shared__ float x_s[T_][H_][17];
  __shared__ float pj_s[JC_][T_][9];
  __shared__ float wg_s[T_][H_][20];
  __shared__ float wl_s[T_][H_][20];
  __shared__ float sg_s[T_][H_], sl_s[T_][H_];
  __shared__ float Wap_s[E_][H_];
  __shared__ float Wep_s[H_][E_];
  __shared__ float Woe_s[E_][36];
  __shared__ float bap_s[E_];
  __shared__ float bep_s[H_];

  const int tid = threadIdx.x;
  const int bid = blockIdx.x;
  // XCD swizzle: batch b -> XCDs {2b, 2b+1}; assumes round-robin bid%8 -> XCD.
  const int xcd = bid & 7, slot = bid >> 3;
  const int b  = xcd >> 1;
  const int i0 = ((((xcd & 1) << 6) | slot)) * T_;
  const int ua = use_adj_p[0];

  // thread mappings
  const int hq = tid >> 5, jcq = (tid >> 1) & 15, df = tid & 1;   // QK
  const int jcE = tid >> 4, ilE = (tid >> 2) & 3, ehE = tid & 3;  // edge
  const int i2 = tid >> 7, hs = (tid >> 4) & 7, jcs = tid & 15;   // softmax
  const int hv = tid >> 5;                                        // PV (col=tid)
  const int wv = tid >> 6, ln = tid & 63;                         // lds-load

  // ---- prologue ----
  { int u = tid;        Wap_s[u>>3][u&7]  = Wap[u]; }             // 256 = E*H
  { int u = tid;        Wep_s[u>>5][u&31] = Wep[u]; }             // 256 = H*E
  for (int u = tid; u < E_*E_; u += 256) Woe_s[u>>5][u&31] = Woe[u];
  if (tid < E_) bap_s[tid] = bap[tid];
  if (tid < H_) bep_s[tid] = bep[tid];
  if (tid < T_*H_) { sg_s[tid>>3][tid&7] = 0.f; sl_s[tid>>3][tid&7] = 0.f; }
  {
    int r = tid >> 6, c4 = (tid & 63) * 4;
    *(float4*)&y_s[r][c4] = *(const float4*)&qin[(size_t)(b*N_ + i0 + r)*HID_ + c4];
  }
  // stage V tile 0 + prefetch chunk-0 operands
  #pragma unroll
  for (int t = 0; t < 4; ++t)
    gload_lds16(&vhp[((size_t)b*N_ + 0 + wv*4 + t)*HID_ + ln*4], &vh_s[0][wv*4+t][0]);
  float4 efp4[2];
  float ab_p[2], a1s_p[2], adj_p[4], a1e_p;
  {
    const float* efsrc = &ef[(((size_t)b*N_ + jcE)*N_ + i0 + ilE)*E_ + ehE*8];
    efp4[0] = *(const float4*)efsrc; efp4[1] = *(const float4*)(efsrc+4);
    #pragma unroll
    for (int tt = 0; tt < 2; ++tt) {
      int i = i2 + 2*tt;
      ab_p[tt]  = ab[(((size_t)b*H_ + hs)*N_ + i0 + i)*N_ + jcs];
      a1s_p[tt] = adj1[((size_t)b*N_ + i0 + i)*N_ + jcs];
    }
    #pragma unroll
    for (int ii = 0; ii < 4; ++ii)
      adj_p[ii] = adj[((size_t)b*N_ + i0 + ii)*N_ + jcq];
    a1e_p = adj1[((size_t)b*N_ + i0 + ilE)*N_ + jcE];
  }
  __syncthreads();

  // ---- q projection: thread = out column, 4 rows ----
  {
    const int cc = tid;
    float a0 = 0.f, a1 = 0.f, a2 = 0.f, a3 = 0.f;
    for (int k = 0; k < HID_; k += 4) {
      float4 w4 = *(const float4*)&Wq[(size_t)cc*HID_ + k];
      a0 += dot4(*(const float4*)&y_s[0][k], w4);
      a1 += dot4(*(const float4*)&y_s[1][k], w4);
      a2 += dot4(*(const float4*)&y_s[2][k], w4);
      a3 += dot4(*(const float4*)&y_s[3][k], w4);
    }
    float bqv = bq[cc];
    qh_s[0][cc] = (a0 + bqv) * SCALE_;
    qh_s[1][cc] = (a1 + bqv) * SCALE_;
    qh_s[2][cc] = (a2 + bqv) * SCALE_;
    qh_s[3][cc] = (a3 + bqv) * SCALE_;
  }
  __syncthreads();

  // q fragments in registers: 4 rows x 16 d (this thread's half of head hq)
  float4 qr[4][4];
  #pragma unroll
  for (int ii = 0; ii < 4; ++ii)
    #pragma unroll
    for (int f = 0; f < 4; ++f)
      qr[ii][f] = *(const float4*)&qh_s[ii][hq*32 + df*16 + f*4];

  float accg[4] = {}, accl[4] = {};

  for (int k = 0; k < NCH_; ++k) {
    const int j0 = k * JC_;
    const int pbuf = k & 1;
    // ======== phase A: QK + Wep projection ========
    {
      const float* kr = &khp[((size_t)b*N_ + j0 + jcq)*HID_ + hq*32 + df*16];
      float4 k0 = *(const float4*)(kr+0),  k1 = *(const float4*)(kr+4);
      float4 k2 = *(const float4*)(kr+8),  k3 = *(const float4*)(kr+12);
      #pragma unroll
      for (int ii = 0; ii < 4; ++ii) {
        float s = dot4(qr[ii][0],k0) + dot4(qr[ii][1],k1)
                + dot4(qr[ii][2],k2) + dot4(qr[ii][3],k3);
        s += __shfl_xor(s, 1, 64);
        if (ua) { float a = adj_p[ii]; s = (a > 0.f ? s : NEG_) * a; }
        x_s[ii][hq][jcq] = s;
      }
    }
    {
      float pp[8];
      #pragma unroll
      for (int h = 0; h < 8; ++h) {
        float4 wa = *(const float4*)&Wep_s[h][ehE*8];
        float4 wb = *(const float4*)&Wep_s[h][ehE*8+4];
        pp[h] = dot4(efp4[0], wa) + dot4(efp4[1], wb);
      }
      #pragma unroll
      for (int h = 0; h < 8; ++h) {
        pp[h] += __shfl_xor(pp[h], 1, 64);
        pp[h] += __shfl_xor(pp[h], 2, 64);
      }
      pj_s[jcE][ilE][ehE*2+0] = pp[ehE*2+0] + bep_s[ehE*2+0];
      pj_s[jcE][ilE][ehE*2+1] = pp[ehE*2+1] + bep_s[ehE*2+1];
    }
    __syncthreads();  // bar1
    // ======== phase B: softmax weights + edge update ========
    {
      #pragma unroll
      for (int tt = 0; tt < 2; ++tt) {
        int i = i2 + 2*tt;
        float xq = x_s[i][hs][jcs];
        float pj = pj_s[jcs][i][hs];
        float eg = __expf(xq * ab_p[tt]);
        float el = __expf(xq * pj * a1s_p[tt]);
        wg_s[i][hs][jcs] = eg;
        wl_s[i][hs][jcs] = el;
        float sgp = eg, slp = el;
        #pragma unroll
        for (int m = 1; m <= 8; m <<= 1) {
          sgp += __shfl_xor(sgp, m, 64);
          slp += __shfl_xor(slp, m, 64);
        }
        if (jcs == 0) { sg_s[i][hs] += sgp; sl_s[i][hs] += slp; }
      }
    }
    {
      float xr[8];
      #pragma unroll
      for (int h = 0; h < 8; ++h) xr[h] = x_s[ilE][h][jcE];
      float efr[8];
      #pragma unroll
      for (int ex = 0; ex < 8; ++ex) {
        int e = ehE*8 + ex;
        float4 wa0 = *(const float4*)&Wap_s[e][0];
        float4 wa1 = *(const float4*)&Wap_s[e][4];
        float xp = bap_s[e]
          + xr[0]*wa0.x + xr[1]*wa0.y + xr[2]*wa0.z + xr[3]*wa0.w
          + xr[4]*wa1.x + xr[5]*wa1.y + xr[6]*wa1.z + xr[7]*wa1.w;
        float efv = ((const float*)&efp4[ex>>2])[ex&3];
        efr[ex] = efv + xp * a1e_p;
      }
      *(float4*)&ef_s[0][jcE][ilE][ehE*4] = make_float4(efr[0],efr[1],efr[2],efr[3]);
      *(float4*)&ef_s[1][jcE][ilE][ehE*4] = make_float4(efr[4],efr[5],efr[6],efr[7]);
    }
    __syncthreads();  // bar2 (drains vh_lds loads issued last chunk)
    // ======== phase C: prefetch k+1, Woe GEMM -> eo, PV accumulate ========
    {
      const int kn = (k < NCH_-1) ? k+1 : NCH_-1;
      const int j0n = kn * JC_;
      const float* efsrc = &ef[(((size_t)b*N_ + j0n + jcE)*N_ + i0 + ilE)*E_ + ehE*8];
      efp4[0] = *(const float4*)efsrc; efp4[1] = *(const float4*)(efsrc+4);
      #pragma unroll
      for (int tt = 0; tt < 2; ++tt) {
        int i = i2 + 2*tt;
        ab_p[tt]  = ab[(((size_t)b*H_ + hs)*N_ + i0 + i)*N_ + j0n + jcs];
        a1s_p[tt] = adj1[((size_t)b*N_ + i0 + i)*N_ + j0n + jcs];
      }
      #pragma unroll
      for (int ii = 0; ii < 4; ++ii)
        adj_p[ii] = adj[((size_t)b*N_ + i0 + ii)*N_ + j0n + jcq];
      a1e_p = adj1[((size_t)b*N_ + i0 + ilE)*N_ + j0n + jcE];
      #pragma unroll
      for (int t = 0; t < 4; ++t)
        gload_lds16(&vhp[((size_t)b*N_ + j0n + wv*4 + t)*HID_ + ln*4],
                    &vh_s[(k+1)&1][wv*4+t][0]);
    }
    {
      float4 tv[8];
      #pragma unroll
      for (int g = 0; g < 8; ++g)
        tv[g] = *(const float4*)&ef_s[g&1][jcE][ilE][(g>>1)*4];
      float o[8];
      #pragma unroll
      for (int ex = 0; ex < 8; ++ex) {
        int ep = ehE*8 + ex;
        float4 s4 = make_float4(0.f,0.f,0.f,0.f);
        #pragma unroll
        for (int g = 0; g < 8; ++g)
          fma4(s4, tv[g], *(const float4*)&Woe_s[ep][g*4]);
        o[ex] = s4.x + s4.y + s4.z + s4.w;
      }
      size_t base = (((size_t)b*N_ + j0 + jcE)*N_ + i0 + ilE)*E_ + ehE*8;
      *(float4*)&eo[base]   = make_float4(o[0],o[1],o[2],o[3]);
      *(float4*)&eo[base+4] = make_float4(o[4],o[5],o[6],o[7]);
    }
    {
      #pragma unroll
      for (int g = 0; g < 4; ++g) {
        float v0 = vh_s[pbuf][g*4+0][tid];
        float v1 = vh_s[pbuf][g*4+1][tid];
        float v2 = vh_s[pbuf][g*4+2][tid];
        float v3 = vh_s[pbuf][g*4+3][tid];
        #pragma unroll
        for (int i = 0; i < 4; ++i) {
          float4 wg4 = *(const float4*)&wg_s[i][hv][g*4];
          float4 wl4 = *(const float4*)&wl_s[i][hv][g*4];
          accg[i] += wg4.x*v0 + wg4.y*v1 + wg4.z*v2 + wg4.w*v3;
          accl[i] += wl4.x*v0 + wl4.y*v1 + wl4.z*v2 + wl4.w*v3;
        }
      }
    }
  }

  // ---- finalize y ----
  #pragma unroll
  for (int i = 0; i < 4; ++i)
    y_s[i][tid] = accg[i]/sg_s[i][hv] + accl[i]/sl_s[i][hv];
  __syncthreads();

  // ---- output projection (Wo) ----
  {
    const int n = tid;
    float a0 = 0.f, a1 = 0.f, a2 = 0.f, a3 = 0.f;
    for (int kx = 0; kx < HID_; kx += 4) {
      float4 w4 = *(const float4*)&Wo[(size_t)n*HID_ + kx];
      a0 += dot4(*(const float4*)&y_s[0][kx], w4);
      a1 += dot4(*(const float4*)&y_s[1][kx], w4);
      a2 += dot4(*(const float4*)&y_s[2][kx], w4);
      a3 += dot4(*(const float4*)&y_s[3][kx], w4);
    }
    float bov = bo[n];
    out[(size_t)(b*N_ + i0 + 0)*HID_ + n] = a0 + bov;
    out[(size_t)(b*N_ + i0 + 1)*HID_ + n] = a1 + bov;
    out[(size_t)(b*N_ + i0 + 2)*HID_ + n] = a2 + bov;
    out[(size_t)(b*N_ + i0 + 3)*HID_ + n] = a3 + bov;
  }
}

extern "C" void kernel_launch(void* const* d_in, const int* in_sizes, int n_in,
                              void* d_out, int out_size, void* d_ws, size_t ws_size,
                              hipStream_t stream) {
  const float* q    = (const float*)d_in[0];
  const float* k    = (const float*)d_in[1];
  const float* v    = (const float*)d_in[2];
  const float* adj  = (const float*)d_in[3];
  const float* adj1 = (const float*)d_in[4];
  const float* ef   = (const float*)d_in[5];
  const float* ab   = (const float*)d_in[6];
  const float* Wq   = (const float*)d_in[7];
  const float* bq   = (const float*)d_in[8];
  const float* Wk   = (const float*)d_in[9];
  const float* bk   = (const float*)d_in[10];
  const float* Wv   = (const float*)d_in[11];
  const float* bv   = (const float*)d_in[12];
  const float* Wap  = (const float*)d_in[13];
  const float* bap  = (const float*)d_in[14];
  const float* Wep  = (const float*)d_in[15];
  const float* bep  = (const float*)d_in[16];
  const float* Wo   = (const float*)d_in[17];
  const float* bo   = (const float*)d_in[18];
  const float* Woe  = (const float*)d_in[19];
  const int* use_adj = (const int*)d_in[20];

  float* out = (float*)d_out;
  float* eo  = out + (size_t)B_*N_*HID_;
  float* kh  = (float*)d_ws;
  float* vh  = kh + (size_t)B_*N_*HID_;

  kv_proj<<<dim3(B_*N_/32, HID_/32, 2), 256, 0, stream>>>(k, v, Wk, bk, Wv, bv, kh, vh);
  fused_graph_attn<<<dim3(B_*N_/T_), 256, 0, stream>>>(
      q, kh, vh, adj, adj1, ef, ab, Wq, bq, Wap, bap, Wep, bep, Wo, bo, Woe,
      use_adj, out, eo);
}

// Round 4
// 387.896 us; speedup vs baseline: 1.9833x; 1.2948x over previous
//
#include <hip/hip_runtime.h>
#include <cstdint>

#define B_ 4
#define N_ 512
#define HID_ 256
#define H_ 8
#define E_ 32
#define T_ 4
#define JC_ 16
#define NCH_ 32
#define SCALE_ 0.17677669529663687f
#define NEG_ (-9.0e15f)

typedef __attribute__((ext_vector_type(8))) short short8;
typedef __attribute__((ext_vector_type(4))) float f32x4;

__device__ __forceinline__ float dot4(const float4 a, const float4 b) {
  return a.x*b.x + a.y*b.y + a.z*b.z + a.w*b.w;
}
__device__ __forceinline__ short f2bf(float f) {
  union { float f; uint32_t u; } v; v.f = f;
  uint32_t r = v.u + 0x7FFF + ((v.u >> 16) & 1);
  return (short)(r >> 16);
}
__device__ __forceinline__ short8 pack8(const float* p) {
  short8 r;
  #pragma unroll
  for (int i = 0; i < 8; ++i) r[i] = f2bf(p[i]);
  return r;
}
__device__ __forceinline__ void gload_lds16(const void* g, void* l) {
  __builtin_amdgcn_global_load_lds(
      (__attribute__((address_space(1))) void*)(g),
      (__attribute__((address_space(3))) void*)(l), 16, 0, 0);
}

// ---------------- q/k/v projection via MFMA ----------------
// grid (32, 4, 3), block 256 (4 waves). Tile 64x64, wave = 16 rows x 64 cols.
__global__ __launch_bounds__(256) void proj3(
    const float* __restrict__ qin, const float* __restrict__ kin, const float* __restrict__ vin,
    const float* __restrict__ Wq, const float* __restrict__ bq,
    const float* __restrict__ Wk, const float* __restrict__ bk,
    const float* __restrict__ Wv, const float* __restrict__ bv,
    float* __restrict__ qh, float* __restrict__ kh, float* __restrict__ vh)
{
  const int z = blockIdx.z;
  const float* A    = z == 0 ? qin : (z == 1 ? kin : vin);
  const float* W    = z == 0 ? Wq  : (z == 1 ? Wk  : Wv);
  const float* bias = z == 0 ? bq  : (z == 1 ? bk  : bv);
  float* dst        = z == 0 ? qh  : (z == 1 ? kh  : vh);
  const float scale = z == 0 ? SCALE_ : 1.f;

  const int w = threadIdx.x >> 6, l = threadIdx.x & 63;
  const int m0 = blockIdx.x * 64 + w * 16;
  const int n0 = blockIdx.y * 64;
  const int cm = l & 15, ck = l >> 4;
  const int arow = m0 + cm;

  f32x4 acc[4] = {{0,0,0,0},{0,0,0,0},{0,0,0,0},{0,0,0,0}};
  for (int k0 = 0; k0 < HID_; k0 += 32) {
    float a8[8];
    *(float4*)&a8[0] = *(const float4*)&A[(size_t)arow*HID_ + k0 + ck*8];
    *(float4*)&a8[4] = *(const float4*)&A[(size_t)arow*HID_ + k0 + ck*8 + 4];
    short8 af = pack8(a8);
    #pragma unroll
    for (int nt = 0; nt < 4; ++nt) {
      int col = n0 + nt*16 + cm;
      float b8[8];
      *(float4*)&b8[0] = *(const float4*)&W[(size_t)col*HID_ + k0 + ck*8];
      *(float4*)&b8[4] = *(const float4*)&W[(size_t)col*HID_ + k0 + ck*8 + 4];
      short8 bf = pack8(b8);
      acc[nt] = __builtin_amdgcn_mfma_f32_16x16x32_bf16(af, bf, acc[nt], 0, 0, 0);
    }
  }
  #pragma unroll
  for (int nt = 0; nt < 4; ++nt) {
    int col = n0 + nt*16 + cm;
    float bb = bias[col];
    #pragma unroll
    for (int j = 0; j < 4; ++j) {
      int r2 = m0 + ck*4 + j;
      dst[(size_t)r2*HID_ + col] = (acc[nt][j] + bb) * scale;
    }
  }
}

// ---------------- fused attention + edge pipeline ----------------
// grid 512 blocks (XCD swizzle), 256 threads, T=4 i-rows per block.
__global__ __launch_bounds__(256, 2) void fused_graph_attn(
    const float* __restrict__ qhp, const float* __restrict__ khp, const float* __restrict__ vhp,
    const float* __restrict__ adj, const float* __restrict__ adj1,
    const float* __restrict__ ef, const float* __restrict__ ab,
    const float* __restrict__ Wap, const float* __restrict__ bap,
    const float* __restrict__ Wep, const float* __restrict__ bep,
    const float* __restrict__ Wo, const float* __restrict__ bo,
    const float* __restrict__ Woe,
    const int* __restrict__ use_adj_p,
    float* __restrict__ out, float* __restrict__ eo)
{
  __shared__ float vh_s[2][JC_][HID_];   // 32 KB, global_load_lds dbuf
  __shared__ short efo_s[2][64*E_];      // orig ef bf16, fragment-order, dbuf
  __shared__ short efu_s[64*E_];         // updated ef bf16, fragment-order
  __shared__ float x_s[T_][H_][17];
  __shared__ float pj_s[JC_][T_][9];
  __shared__ float wg_s[T_][H_][20];
  __shared__ float wl_s[T_][H_][20];
  __shared__ float sg_s[T_][H_], sl_s[T_][H_];
  __shared__ float Wap_s[E_][H_];
  __shared__ float y_s[T_][HID_+4];

  const int tid = threadIdx.x;
  const int w = tid >> 6, l = tid & 63;
  const int bid = blockIdx.x;
  const int xcd = bid & 7, slot = bid >> 3;
  const int b  = xcd >> 1;
  const int i0 = (((xcd & 1) << 6) | slot) * T_;
  const int ua = use_adj_p[0];

  // thread mappings
  const int hq = tid >> 5, jcq = (tid >> 1) & 15, df = tid & 1;   // QK
  const int jcE = l >> 2, ilE = l & 3;                            // ef row (wave w = e-block)
  const int i2 = tid >> 7, hs = (tid >> 4) & 7, jcs = tid & 15;   // softmax
  const int hv = tid >> 5;                                        // PV (col = tid)
  const int eslot = (l >> 4) * 64 + w * 16 + (l & 15);            // frag write slot
  const int aslot = w * 64 + l;                                   // frag read slot
  const int cm = l & 15, ck = l >> 4;                             // mfma n / k-block

  // ---- prologue ----
  Wap_s[tid >> 3][tid & 7] = Wap[tid];    // E*H = 256
  float bap_r[8];
  *(float4*)&bap_r[0] = *(const float4*)&bap[w*8];
  *(float4*)&bap_r[4] = *(const float4*)&bap[w*8 + 4];
  float bep_r = (cm < H_) ? bep[cm] : 0.f;

  short8 wep_f;
  #pragma unroll
  for (int j = 0; j < 8; ++j)
    wep_f[j] = (cm < H_) ? f2bf(Wep[cm*E_ + ck*8 + j]) : (short)0;
  short8 woe_f[2];
  #pragma unroll
  for (int t = 0; t < 2; ++t)
    #pragma unroll
    for (int j = 0; j < 8; ++j)
      woe_f[t][j] = f2bf(Woe[(cm + 16*t)*E_ + ck*8 + j]);

  // q fragments (4 rows x 16 d of head hq, half df)
  float4 qr[4][4];
  #pragma unroll
  for (int ii = 0; ii < T_; ++ii)
    #pragma unroll
    for (int f = 0; f < 4; ++f)
      qr[ii][f] = *(const float4*)&qhp[(size_t)(b*N_ + i0 + ii)*HID_ + hq*32 + df*16 + f*4];

  // chunk-0 prefetches
  float efp[8], efn[8];
  {
    const float* p = &ef[(((size_t)b*N_ + jcE)*N_ + i0 + ilE)*E_ + w*8];
    *(float4*)&efp[0] = *(const float4*)p;
    *(float4*)&efp[4] = *(const float4*)(p + 4);
  }
  *(short8*)&efo_s[0][eslot*8] = pack8(efp);
  float ab_p[2], a1s_p[2], adj_p[4], a1e_p;
  #pragma unroll
  for (int tt = 0; tt < 2; ++tt) {
    int i = i2 + 2*tt;
    ab_p[tt]  = ab[(((size_t)b*H_ + hs)*N_ + i0 + i)*N_ + jcs];
    a1s_p[tt] = adj1[((size_t)b*N_ + i0 + i)*N_ + jcs];
  }
  #pragma unroll
  for (int ii = 0; ii < 4; ++ii)
    adj_p[ii] = adj[((size_t)b*N_ + i0 + ii)*N_ + jcq];
  a1e_p = adj1[((size_t)b*N_ + i0 + ilE)*N_ + jcE];
  float4 kr[4];
  #pragma unroll
  for (int f = 0; f < 4; ++f)
    kr[f] = *(const float4*)&khp[((size_t)b*N_ + jcq)*HID_ + hq*32 + df*16 + f*4];
  #pragma unroll
  for (int t = 0; t < 4; ++t)
    gload_lds16(&vhp[((size_t)b*N_ + w*4 + t)*HID_ + l*4], &vh_s[0][w*4+t][0]);

  if (tid < T_*H_) { sg_s[tid>>3][tid&7] = 0.f; sl_s[tid>>3][tid&7] = 0.f; }
  __syncthreads();

  float accg[4] = {}, accl[4] = {};
  float sgr[2] = {}, slr[2] = {};
  const f32x4 zero4 = {0.f, 0.f, 0.f, 0.f};

  for (int k = 0; k < NCH_; ++k) {
    const int j0 = k * JC_;
    const int kn = (k + 1 < NCH_) ? k + 1 : k;
    const int j0n = kn * JC_;
    const int buf = k & 1;
    // ======== phase A: ef[k+1] issue, QK, Wep-MFMA ========
    {
      const float* p = &ef[(((size_t)b*N_ + j0n + jcE)*N_ + i0 + ilE)*E_ + w*8];
      *(float4*)&efn[0] = *(const float4*)p;
      *(float4*)&efn[4] = *(const float4*)(p + 4);
    }
    #pragma unroll
    for (int ii = 0; ii < T_; ++ii) {
      float s = dot4(qr[ii][0],kr[0]) + dot4(qr[ii][1],kr[1])
              + dot4(qr[ii][2],kr[2]) + dot4(qr[ii][3],kr[3]);
      s += __shfl_xor(s, 1, 64);
      if (ua) { float a = adj_p[ii]; s = (a > 0.f ? s : NEG_) * a; }
      if (df == 0) x_s[ii][hq][jcq] = s;
    }
    {
      short8 af = *(const short8*)&efo_s[buf][aslot*8];
      f32x4 pj4 = __builtin_amdgcn_mfma_f32_16x16x32_bf16(af, wep_f, zero4, 0, 0, 0);
      if (cm < H_) {
        #pragma unroll
        for (int j = 0; j < 4; ++j) {
          int r = w*16 + ck*4 + j;
          pj_s[r>>2][r&3][cm] = pj4[j] + bep_r;
        }
      }
    }
    __syncthreads();  // bar1
    // ======== phase B: softmax weights + edge update ========
    #pragma unroll
    for (int tt = 0; tt < 2; ++tt) {
      int i = i2 + 2*tt;
      float xq = x_s[i][hs][jcs];
      float pj = pj_s[jcs][i][hs];
      float eg = __expf(xq * ab_p[tt]);
      float el = __expf(xq * pj * a1s_p[tt]);
      wg_s[i][hs][jcs] = eg;
      wl_s[i][hs][jcs] = el;
      float sgp = eg, slp = el;
      #pragma unroll
      for (int m = 1; m <= 8; m <<= 1) {
        sgp += __shfl_xor(sgp, m, 64);
        slp += __shfl_xor(slp, m, 64);
      }
      if (jcs == 0) { sgr[tt] += sgp; slr[tt] += slp; }
    }
    {
      float xr[8];
      #pragma unroll
      for (int h = 0; h < H_; ++h) xr[h] = x_s[ilE][h][jcE];
      float efr[8];
      #pragma unroll
      for (int ex = 0; ex < 8; ++ex) {
        int e = w*8 + ex;
        float4 wa0 = *(const float4*)&Wap_s[e][0];
        float4 wa1 = *(const float4*)&Wap_s[e][4];
        float xp = bap_r[ex]
          + xr[0]*wa0.x + xr[1]*wa0.y + xr[2]*wa0.z + xr[3]*wa0.w
          + xr[4]*wa1.x + xr[5]*wa1.y + xr[6]*wa1.z + xr[7]*wa1.w;
        efr[ex] = efp[ex] + xp * a1e_p;
      }
      *(short8*)&efu_s[eslot*8] = pack8(efr);
      *(short8*)&efo_s[buf^1][eslot*8] = pack8(efn);
      #pragma unroll
      for (int ex = 0; ex < 8; ++ex) efp[ex] = efn[ex];
    }
    __syncthreads();  // bar2
    // ======== phase C: prefetch k+1, Woe-MFMA -> eo, PV ========
    if (k + 1 < NCH_) {
      #pragma unroll
      for (int t = 0; t < 4; ++t)
        gload_lds16(&vhp[((size_t)b*N_ + j0n + w*4 + t)*HID_ + l*4],
                    &vh_s[(k+1) & 1][w*4+t][0]);
    }
    #pragma unroll
    for (int tt = 0; tt < 2; ++tt) {
      int i = i2 + 2*tt;
      ab_p[tt]  = ab[(((size_t)b*H_ + hs)*N_ + i0 + i)*N_ + j0n + jcs];
      a1s_p[tt] = adj1[((size_t)b*N_ + i0 + i)*N_ + j0n + jcs];
    }
    #pragma unroll
    for (int ii = 0; ii < 4; ++ii)
      adj_p[ii] = adj[((size_t)b*N_ + i0 + ii)*N_ + j0n + jcq];
    a1e_p = adj1[((size_t)b*N_ + i0 + ilE)*N_ + j0n + jcE];
    #pragma unroll
    for (int f = 0; f < 4; ++f)
      kr[f] = *(const float4*)&khp[((size_t)b*N_ + j0n + jcq)*HID_ + hq*32 + df*16 + f*4];
    {
      short8 au = *(const short8*)&efu_s[aslot*8];
      #pragma unroll
      for (int t = 0; t < 2; ++t) {
        f32x4 oc = __builtin_amdgcn_mfma_f32_16x16x32_bf16(au, woe_f[t], zero4, 0, 0, 0);
        #pragma unroll
        for (int j = 0; j < 4; ++j) {
          int r = w*16 + ck*4 + j;
          eo[(((size_t)b*N_ + j0 + (r>>2))*N_ + i0 + (r&3))*E_ + cm + 16*t] = oc[j];
        }
      }
    }
    {
      #pragma unroll
      for (int g = 0; g < 4; ++g) {
        float v0 = vh_s[buf][g*4+0][tid];
        float v1 = vh_s[buf][g*4+1][tid];
        float v2 = vh_s[buf][g*4+2][tid];
        float v3 = vh_s[buf][g*4+3][tid];
        #pragma unroll
        for (int i = 0; i < 4; ++i) {
          float4 wg4 = *(const float4*)&wg_s[i][hv][g*4];
          float4 wl4 = *(const float4*)&wl_s[i][hv][g*4];
          accg[i] += wg4.x*v0 + wg4.y*v1 + wg4.z*v2 + wg4.w*v3;
          accl[i] += wl4.x*v0 + wl4.y*v1 + wl4.z*v2 + wl4.w*v3;
        }
      }
    }
  }

  // ---- finalize ----
  if (jcs == 0) {
    #pragma unroll
    for (int tt = 0; tt < 2; ++tt) {
      sg_s[i2 + 2*tt][hs] = sgr[tt];
      sl_s[i2 + 2*tt][hs] = slr[tt];
    }
  }
  __syncthreads();
  #pragma unroll
  for (int i = 0; i < T_; ++i)
    y_s[i][tid] = accg[i]/sg_s[i][hv] + accl[i]/sl_s[i][hv];
  __syncthreads();

  // ---- output projection (Wo) ----
  {
    const int n = tid;
    float a0 = 0.f, a1 = 0.f, a2 = 0.f, a3 = 0.f;
    for (int kx = 0; kx < HID_; kx += 4) {
      float4 w4 = *(const float4*)&Wo[(size_t)n*HID_ + kx];
      a0 += dot4(*(const float4*)&y_s[0][kx], w4);
      a1 += dot4(*(const float4*)&y_s[1][kx], w4);
      a2 += dot4(*(const float4*)&y_s[2][kx], w4);
      a3 += dot4(*(const float4*)&y_s[3][kx], w4);
    }
    float bov = bo[n];
    out[(size_t)(b*N_ + i0 + 0)*HID_ + n] = a0 + bov;
    out[(size_t)(b*N_ + i0 + 1)*HID_ + n] = a1 + bov;
    out[(size_t)(b*N_ + i0 + 2)*HID_ + n] = a2 + bov;
    out[(size_t)(b*N_ + i0 + 3)*HID_ + n] = a3 + bov;
  }
}

extern "C" void kernel_launch(void* const* d_in, const int* in_sizes, int n_in,
                              void* d_out, int out_size, void* d_ws, size_t ws_size,
                              hipStream_t stream) {
  const float* q    = (const float*)d_in[0];
  const float* k    = (const float*)d_in[1];
  const float* v    = (const float*)d_in[2];
  const float* adj  = (const float*)d_in[3];
  const float* adj1 = (const float*)d_in[4];
  const float* ef   = (const float*)d_in[5];
  const float* ab   = (const float*)d_in[6];
  const float* Wq   = (const float*)d_in[7];
  const float* bq   = (const float*)d_in[8];
  const float* Wk   = (const float*)d_in[9];
  const float* bk   = (const float*)d_in[10];
  const float* Wv   = (const float*)d_in[11];
  const float* bv   = (const float*)d_in[12];
  const float* Wap  = (const float*)d_in[13];
  const float* bap  = (const float*)d_in[14];
  const float* Wep  = (const float*)d_in[15];
  const float* bep  = (const float*)d_in[16];
  const float* Wo   = (const float*)d_in[17];
  const float* bo   = (const float*)d_in[18];
  const float* Woe  = (const float*)d_in[19];
  const int* use_adj = (const int*)d_in[20];

  float* out = (float*)d_out;
  float* eo  = out + (size_t)B_*N_*HID_;
  float* qh  = (float*)d_ws;
  float* kh  = qh + (size_t)B_*N_*HID_;
  float* vh  = kh + (size_t)B_*N_*HID_;

  proj3<<<dim3(B_*N_/64, HID_/64, 3), 256, 0, stream>>>(
      q, k, v, Wq, bq, Wk, bk, Wv, bv, qh, kh, vh);
  fused_graph_attn<<<dim3(B_*N_/T_), 256, 0, stream>>>(
      qh, kh, vh, adj, adj1, ef, ab, Wap, bap, Wep, bep, Wo, bo, Woe,
      use_adj, out, eo);
}